// Round 4
// baseline (17.233 us; speedup 1.0000x reference)
//
#include <hip/hip_runtime.h>

#define NP 96
#define NREAL 95
#define NLAB 8
#define SINK_ITERS 10
#define HW 7           // histogram waves (waves 1..7), private LDS copies

// ---------------------------------------------------------------------------
// Single fused kernel, one block of 512 threads (8 waves).
//
// M0[i,k] = W[a_i][b_k], W = exp(-0.5*NCx), so Sinkhorn is per-LABEL:
//   S[i,k] = R[a_i] * W[a_i][b_k] * C[b_k]
//   R = 1/(W (cnt2.*C)),  C = 1/(W^T (cnt1.*R))          (9-dim, 10 iters)
//
// ged = 0.5*Q2 + L:
//   L  = sum_{a,b} cnt1[a] cnt2[b] NCx[a,b] w(a,b),   w = diag(R) W diag(C)
//   Q2 = sum_{e,f} EC[e,f] sum_{β,δ} P1[e][β][δ] T2[f][β][δ]
//   P1[e][β][δ] = sum_α E1[e][α][β] w(α,δ);  T2[f][β][δ] = sum_γ E2[f][γ][δ] w(β,γ)
//   E1[e][α][β] = #{(p,q): a1[p,q]=e, lab α,β}  (4x9x9), similarly E2.
//
// Wave 0: lane-parallel 9-dim Sinkhorn (lane a owns R[a],C[a]; shfl broadcast).
// Waves 1-7: E1/E2 histograms, 2 threads/row, 7 private LDS copies.
// ---------------------------------------------------------------------------
__global__ __launch_bounds__(512) void ged_fused(
    const int* __restrict__ A1, const int* __restrict__ A2,
    const int* __restrict__ l1, const int* __restrict__ l2,
    const float* __restrict__ nodeW, const float* __restrict__ edgeW,
    float* __restrict__ out)
{
    __shared__ float Wt[9][9];          // exp(-0.5*NCx)
    __shared__ float NC[9][9];          // NCx
    __shared__ float EC[4][4];
    __shared__ int   cnt1r[9], cnt2r[9];
    __shared__ unsigned char lab1[NREAL], lab2[NREAL];
    __shared__ int   E1p[HW][4][9][9], E2p[HW][4][9][9];
    __shared__ float E1f[4][9][9], E2f[4][9][9];
    __shared__ float RC[18];            // R[0..8], C[0..8]
    __shared__ float wfin[9][9];
    __shared__ float P1[4][9][9], T2[4][9][9];
    __shared__ float Lred[8];

    const int t = threadIdx.x;
    const int lane = t & 63;
    const int wave = t >> 6;

    // ---- zero counters ----
    if (t < 9) { cnt1r[t] = 0; cnt2r[t] = 0; }
    for (int e = t; e < HW * 324; e += 512) {
        ((int*)E1p)[e] = 0;
        ((int*)E2p)[e] = 0;
    }

    // ---- cost tables ----
    if (t < 81) {
        int r = t / 9, c = t % 9;
        float v;
        if (r == c) v = 0.f;
        else if (r == NLAB || c == NLAB) v = fmaxf(nodeW[28], 0.f);
        else {
            int rr = min(r, c), cc = max(r, c);
            int p = rr * (15 - rr) / 2 + (cc - rr - 1);   // triu_indices(8,1)
            v = fmaxf(nodeW[p], 0.f);
        }
        NC[r][c] = v;
        Wt[r][c] = expf(-0.5f * v);
    }
    if (t < 16) {
        int r = t / 4, c = t % 4;
        float v;
        if (r == c) v = 0.f;
        else if (r == 0 || c == 0) v = fmaxf(edgeW[3], 0.f);
        else {
            int rr = min(r, c) - 1, cc = max(r, c) - 1;
            int p = rr * (5 - rr) / 2 + (cc - rr - 1);    // triu_indices(3,1)
            v = fmaxf(edgeW[p], 0.f);
        }
        EC[r][c] = v;
    }
    __syncthreads();

    // ---- labels + counts ----
    if (t < NREAL) {
        int a = l1[t], b = l2[t];
        lab1[t] = (unsigned char)a;
        lab2[t] = (unsigned char)b;
        atomicAdd(&cnt1r[a], 1);
        atomicAdd(&cnt2r[b], 1);
    }
    __syncthreads();

    if (wave == 0) {
        // ---- lane-parallel 9-dim Sinkhorn: lane a owns R[a], C[a] ----
        const int a = (lane < 9) ? lane : 0;
        float w1[9], w2[9];
        #pragma unroll
        for (int b = 0; b < 9; ++b) {
            float c2b = (float)cnt2r[b] + (b == 8 ? 1.f : 0.f);
            float c1b = (float)cnt1r[b] + (b == 8 ? 1.f : 0.f);
            w1[b] = Wt[a][b] * c2b;   // row a, pre-scaled by cnt2
            w2[b] = Wt[b][a] * c1b;   // col a, pre-scaled by cnt1
        }
        float Cm = 1.f, Rm = 1.f;
        for (int it = 0; it < SINK_ITERS; ++it) {
            float acc = 0.f;
            #pragma unroll
            for (int b = 0; b < 9; ++b) acc += w1[b] * __shfl(Cm, b, 64);
            Rm = 1.f / acc;
            acc = 0.f;
            #pragma unroll
            for (int x = 0; x < 9; ++x) acc += w2[x] * __shfl(Rm, x, 64);
            Cm = 1.f / acc;
        }
        if (lane < 9) { RC[lane] = Rm; RC[9 + lane] = Cm; }
    } else {
        // ---- E1/E2 histograms: 2 threads per row, 7 private copies ----
        const int hw = wave - 1;           // 0..6
        const int lt = t - 64;             // 0..447
        const unsigned char* labs = 0;
        const int* rowp = 0;
        int* hist = 0;
        int p = 0, h = 0;
        if (lt < 190) {
            p = lt >> 1; h = lt & 1;
            labs = lab1; rowp = A1 + p * NREAL; hist = (int*)E1p[hw];
        } else if (lt >= 192 && lt < 382) {
            int u = lt - 192;
            p = u >> 1; h = u & 1;
            labs = lab2; rowp = A2 + p * NREAL; hist = (int*)E2p[hw];
        }
        if (hist) {
            const int alpha = labs[p];
            const int base = alpha * 9;
            const int qlo = h ? 48 : 0, qhi = h ? 95 : 48;
            for (int q = qlo; q < qhi; ++q) {
                int e = rowp[q];
                atomicAdd(&hist[e * 81 + base + labs[q]], 1);
            }
        }
    }
    __syncthreads();

    // ---- merge private histograms ----
    for (int idx = t; idx < 324; idx += 512) {
        int s1 = 0, s2 = 0;
        #pragma unroll
        for (int c = 0; c < HW; ++c) {
            s1 += ((int*)E1p)[c * 324 + idx];
            s2 += ((int*)E2p)[c * 324 + idx];
        }
        E1f[0][0][idx] = (float)s1;
        E2f[0][0][idx] = (float)s2;
    }
    __syncthreads();

    // ---- padding corrections (row 95 / col 95 / corner, all code 0) ----
    if (t < 9) {
        E1f[0][8][t] += (float)cnt1r[t];
        E1f[0][t][8] += (float)cnt1r[t];
        E2f[0][8][t] += (float)cnt2r[t];
        E2f[0][t][8] += (float)cnt2r[t];
        if (t == 8) { E1f[0][8][8] += 1.f; E2f[0][8][8] += 1.f; }
    }
    __syncthreads();

    // ---- w(a,b) + linear term ----
    float Lpart = 0.f;
    if (t < 81) {
        int a = t / 9, b = t % 9;
        float wv = RC[a] * Wt[a][b] * RC[9 + b];
        wfin[a][b] = wv;
        float c1f = (float)cnt1r[a] + (a == 8 ? 1.f : 0.f);
        float c2f = (float)cnt2r[b] + (b == 8 ? 1.f : 0.f);
        Lpart = c1f * c2f * NC[a][b] * wv;
    }
    #pragma unroll
    for (int off = 32; off >= 1; off >>= 1) Lpart += __shfl_xor(Lpart, off, 64);
    if (lane == 0) Lred[wave] = Lpart;
    __syncthreads();   // also orders wfin before P1/T2

    // ---- contractions ----
    for (int idx = t; idx < 324; idx += 512) {
        int e = idx / 81, r = idx % 81;
        int beta = r / 9, delta = r % 9;
        float acc1 = 0.f, acc2 = 0.f;
        #pragma unroll
        for (int g = 0; g < 9; ++g) {
            acc1 += E1f[e][g][beta] * wfin[g][delta];
            acc2 += E2f[e][g][delta] * wfin[beta][g];
        }
        P1[e][beta][delta] = acc1;
        T2[e][beta][delta] = acc2;
    }
    __syncthreads();

    // ---- Q2 + output ----
    float qpart = 0.f;
    if (t < 16) {
        int e = t / 4, f = t % 4;
        float acc = 0.f;
        #pragma unroll
        for (int bd = 0; bd < 81; ++bd) {
            int beta = bd / 9, delta = bd % 9;
            acc += P1[e][beta][delta] * T2[f][beta][delta];
        }
        qpart = EC[e][f] * acc;
    }
    #pragma unroll
    for (int off = 8; off >= 1; off >>= 1) qpart += __shfl_xor(qpart, off, 64);
    if (t == 0) {
        float L = 0.f;
        #pragma unroll
        for (int w = 0; w < 8; ++w) L += Lred[w];
        out[0] = 0.5f * qpart + L;
    }
}

extern "C" void kernel_launch(void* const* d_in, const int* in_sizes, int n_in,
                              void* d_out, int out_size, void* d_ws, size_t ws_size,
                              hipStream_t stream) {
    const int*   A1    = (const int*)d_in[0];
    const int*   A2    = (const int*)d_in[1];
    const int*   l1    = (const int*)d_in[2];
    const int*   l2    = (const int*)d_in[3];
    const float* nodeW = (const float*)d_in[4];
    const float* edgeW = (const float*)d_in[5];
    float* out = (float*)d_out;

    hipLaunchKernelGGL(ged_fused, dim3(1), dim3(512), 0, stream,
                       A1, A2, l1, l2, nodeW, edgeW, out);
}

// Round 5
// 16.114 us; speedup vs baseline: 1.0694x; 1.0694x over previous
//
#include <hip/hip_runtime.h>

#define NP 96
#define NREAL 95
#define NLAB 8
#define SINK_ITERS 10

// ---------------------------------------------------------------------------
// Single fused kernel, one block of 256 threads (best-measured variant, R3).
//
// M0[i,k] = W[a_i][b_k], W = exp(-0.5*NCx), so Sinkhorn is per-LABEL:
//   S[i,k] = R[a_i] * W[a_i][b_k] * C[b_k]
//   R = 1/(W (cnt2.*C)),  C = 1/(W^T (cnt1.*R))          (9-dim, 10 iters)
//
// ged = 0.5*Q2 + L:
//   L  = sum_{a,b} cnt1[a] cnt2[b] NCx[a,b] w(a,b),   w = diag(R) W diag(C)
//   Q2 = sum_{e,f} EC[e,f] sum_{β,δ} P1[e][β][δ] T2[f][β][δ]
//   P1[e][β][δ] = sum_α E1[e][α][β] w(α,δ);  T2[f][β][δ] = sum_γ E2[f][γ][δ] w(β,γ)
//   E1[e][α][β] = #{(p,q): a1[p,q]=e, lab α,β}  (4x9x9), similarly E2.
//
// Wave 0: 9-dim Sinkhorn in registers (runs concurrently with histograms;
// critical path is the histogram phase). Waves 1-3: E1/E2 histograms into
// per-wave private LDS copies.
// ---------------------------------------------------------------------------
__global__ __launch_bounds__(256) void ged_fused(
    const int* __restrict__ A1, const int* __restrict__ A2,
    const int* __restrict__ l1, const int* __restrict__ l2,
    const float* __restrict__ nodeW, const float* __restrict__ edgeW,
    float* __restrict__ out)
{
    __shared__ float Wt[9][9];          // exp(-0.5*NCx)
    __shared__ float NC[9][9];          // NCx
    __shared__ float EC[4][4];
    __shared__ int   cnt1r[9], cnt2r[9];
    __shared__ unsigned char lab1[NREAL], lab2[NREAL];
    __shared__ int   E1p[3][4][9][9], E2p[3][4][9][9];  // per-wave private hists
    __shared__ float E1f[4][9][9], E2f[4][9][9];
    __shared__ float RC[18];            // R[0..8], C[0..8]
    __shared__ float wfin[9][9];
    __shared__ float P1[4][9][9], T2[4][9][9];
    __shared__ float Lred[4];

    const int t = threadIdx.x;
    const int lane = t & 63;
    const int wave = t >> 6;

    // ---- zero counters ----
    if (t < 9) { cnt1r[t] = 0; cnt2r[t] = 0; }
    for (int e = t; e < 3 * 324; e += 256) {
        ((int*)E1p)[e] = 0;
        ((int*)E2p)[e] = 0;
    }

    // ---- cost tables ----
    if (t < 81) {
        int r = t / 9, c = t % 9;
        float v;
        if (r == c) v = 0.f;
        else if (r == NLAB || c == NLAB) v = fmaxf(nodeW[28], 0.f);
        else {
            int rr = min(r, c), cc = max(r, c);
            int p = rr * (15 - rr) / 2 + (cc - rr - 1);   // triu_indices(8,1)
            v = fmaxf(nodeW[p], 0.f);
        }
        NC[r][c] = v;
        Wt[r][c] = expf(-0.5f * v);
    }
    if (t < 16) {
        int r = t / 4, c = t % 4;
        float v;
        if (r == c) v = 0.f;
        else if (r == 0 || c == 0) v = fmaxf(edgeW[3], 0.f);
        else {
            int rr = min(r, c) - 1, cc = max(r, c) - 1;
            int p = rr * (5 - rr) / 2 + (cc - rr - 1);    // triu_indices(3,1)
            v = fmaxf(edgeW[p], 0.f);
        }
        EC[r][c] = v;
    }
    __syncthreads();

    // ---- labels + counts ----
    if (t < NREAL) {
        int a = l1[t], b = l2[t];
        lab1[t] = (unsigned char)a;
        lab2[t] = (unsigned char)b;
        atomicAdd(&cnt1r[a], 1);
        atomicAdd(&cnt2r[b], 1);
    }
    __syncthreads();

    if (wave == 0) {
        // ================= Sinkhorn, 9-dim, in registers =================
        float w[9][9];
        #pragma unroll
        for (int a = 0; a < 9; ++a)
            #pragma unroll
            for (int b = 0; b < 9; ++b) w[a][b] = Wt[a][b];
        float c1[9], c2[9];
        #pragma unroll
        for (int a = 0; a < 9; ++a) {
            c1[a] = (float)cnt1r[a] + (a == 8 ? 1.f : 0.f);  // + eps node
            c2[a] = (float)cnt2r[a] + (a == 8 ? 1.f : 0.f);
        }
        float C[9], R[9];
        #pragma unroll
        for (int b = 0; b < 9; ++b) C[b] = 1.f;
        for (int it = 0; it < SINK_ITERS; ++it) {
            float s[9];
            #pragma unroll
            for (int b = 0; b < 9; ++b) s[b] = c2[b] * C[b];
            #pragma unroll
            for (int a = 0; a < 9; ++a) {
                float acc = 0.f;
                #pragma unroll
                for (int b = 0; b < 9; ++b) acc += w[a][b] * s[b];
                R[a] = 1.f / acc;
            }
            float r2[9];
            #pragma unroll
            for (int a = 0; a < 9; ++a) r2[a] = c1[a] * R[a];
            #pragma unroll
            for (int b = 0; b < 9; ++b) {
                float acc = 0.f;
                #pragma unroll
                for (int a = 0; a < 9; ++a) acc += w[a][b] * r2[a];
                C[b] = 1.f / acc;
            }
        }
        if (lane == 0) {
            #pragma unroll
            for (int a = 0; a < 9; ++a) { RC[a] = R[a]; RC[9 + a] = C[a]; }
        }
    } else {
        // ================= E1/E2 histograms (waves 1-3) =================
        const int hw = wave - 1;       // private copy 0..2
        const int lt = t - 64;         // 0..191
        if (lt < NREAL) {
            int p = lt;
            int alpha = lab1[p];
            const int* __restrict__ row = A1 + p * NREAL;
            for (int q = 0; q < NREAL; ++q) {
                int e = row[q];
                atomicAdd(&E1p[hw][e][alpha][lab1[q]], 1);
            }
        } else if (lt >= 96 && lt < 96 + NREAL) {
            int p = lt - 96;
            int gamma = lab2[p];
            const int* __restrict__ row = A2 + p * NREAL;
            for (int q = 0; q < NREAL; ++q) {
                int f = row[q];
                atomicAdd(&E2p[hw][f][gamma][lab2[q]], 1);
            }
        }
    }
    __syncthreads();

    // ---- combine private histograms to float ----
    for (int idx = t; idx < 324; idx += 256) {
        E1f[0][0][idx] = (float)(((int*)E1p[0])[idx] + ((int*)E1p[1])[idx] + ((int*)E1p[2])[idx]);
        E2f[0][0][idx] = (float)(((int*)E2p[0])[idx] + ((int*)E2p[1])[idx] + ((int*)E2p[2])[idx]);
    }
    __syncthreads();

    // ---- padding corrections: row 95, col 95, corner (all e=0) ----
    if (t < 9) {
        E1f[0][8][t] += (float)cnt1r[t];      // (95, q): α=8, β=lab1[q]
        E1f[0][t][8] += (float)cnt1r[t];      // (p, 95): β=8
        E2f[0][8][t] += (float)cnt2r[t];
        E2f[0][t][8] += (float)cnt2r[t];
        if (t == 8) { E1f[0][8][8] += 1.f; E2f[0][8][8] += 1.f; }  // corner
    }
    __syncthreads();

    // ---- final w(a,b) + linear term ----
    float Lpart = 0.f;
    if (t < 81) {
        int a = t / 9, b = t % 9;
        float wv = RC[a] * Wt[a][b] * RC[9 + b];
        wfin[a][b] = wv;
        float c1f = (float)cnt1r[a] + (a == 8 ? 1.f : 0.f);
        float c2f = (float)cnt2r[b] + (b == 8 ? 1.f : 0.f);
        Lpart = c1f * c2f * NC[a][b] * wv;
    }
    #pragma unroll
    for (int off = 32; off >= 1; off >>= 1) Lpart += __shfl_xor(Lpart, off, 64);
    if (lane == 0) Lred[wave] = Lpart;
    __syncthreads();   // also orders wfin before P1/T2 reads

    // ---- contractions: P1[e][β][δ] = Σ_α E1[e][α][β] w(α,δ)
    //                    T2[f][β][δ] = Σ_γ E2[f][γ][δ] w(β,γ)
    for (int idx = t; idx < 324; idx += 256) {
        int e = idx / 81, r = idx % 81;
        int beta = r / 9, delta = r % 9;
        float acc1 = 0.f, acc2 = 0.f;
        #pragma unroll
        for (int g = 0; g < 9; ++g) {
            acc1 += E1f[e][g][beta] * wfin[g][delta];
            acc2 += E2f[e][g][delta] * wfin[beta][g];
        }
        P1[e][beta][delta] = acc1;
        T2[e][beta][delta] = acc2;
    }
    __syncthreads();

    // ---- Q2 = Σ_{e,f} EC[e,f] Σ_{β,δ} P1[e][β][δ] T2[f][β][δ] ----
    float qpart = 0.f;
    if (t < 16) {
        int e = t / 4, f = t % 4;
        float acc = 0.f;
        #pragma unroll
        for (int bd = 0; bd < 81; ++bd) {
            int beta = bd / 9, delta = bd % 9;
            acc += P1[e][beta][delta] * T2[f][beta][delta];
        }
        qpart = EC[e][f] * acc;
    }
    #pragma unroll
    for (int off = 8; off >= 1; off >>= 1) qpart += __shfl_xor(qpart, off, 64);
    if (t == 0) {
        float L = Lred[0] + Lred[1] + Lred[2] + Lred[3];
        out[0] = 0.5f * qpart + L;
    }
}

extern "C" void kernel_launch(void* const* d_in, const int* in_sizes, int n_in,
                              void* d_out, int out_size, void* d_ws, size_t ws_size,
                              hipStream_t stream) {
    const int*   A1    = (const int*)d_in[0];
    const int*   A2    = (const int*)d_in[1];
    const int*   l1    = (const int*)d_in[2];
    const int*   l2    = (const int*)d_in[3];
    const float* nodeW = (const float*)d_in[4];
    const float* edgeW = (const float*)d_in[5];
    float* out = (float*)d_out;

    hipLaunchKernelGGL(ged_fused, dim3(1), dim3(256), 0, stream,
                       A1, A2, l1, l2, nodeW, edgeW, out);
}